// Round 8
// baseline (134.755 us; speedup 1.0000x reference)
//
#include <hip/hip_runtime.h>

#define BB 4
#define TQ 512
#define TK 512
#define DQ 512
#define UU 256
#define KH (DQ / 2)
#define CSC 2.8853900817779268f   // 2*log2(e), folded into W so x = 2log2e*(q+k)
#define L2E 1.4426950408889634f
#define RQ 2
#define WS_NEED 13635584

typedef unsigned short u16;
typedef float f2 __attribute__((ext_vector_type(2)));
typedef short bf16x8 __attribute__((ext_vector_type(8)));
typedef float f32x4 __attribute__((ext_vector_type(4)));

__device__ __forceinline__ float fexp2(float x) { return __builtin_amdgcn_exp2f(x); }
__device__ __forceinline__ float frcp(float x)  { return __builtin_amdgcn_rcpf(x); }
__device__ __forceinline__ u16 f2bf(float x) {
    unsigned u = __float_as_uint(x);
    u = (u + 0x7FFFu + ((u >> 16) & 1u)) >> 16;
    return (u16)u;
}
__device__ __forceinline__ float bf2f(u16 h) { return __uint_as_float(((unsigned)h) << 16); }

// ---- convert: fp32 -> split bf16 (hi + lo). A planes unscaled; W planes scaled by
// CSC and transposed to [n][k]. Last block writes scale2 = -2*scale.
__global__ __launch_bounds__(256) void convert(
    const float* __restrict__ query, const float* __restrict__ value,
    const float* __restrict__ W1, const float* __restrict__ W2,
    const float* __restrict__ scale,
    u16* __restrict__ Aqh, u16* __restrict__ Aql,
    u16* __restrict__ Avh, u16* __restrict__ Avl,
    u16* __restrict__ W1h, u16* __restrict__ W1l,
    u16* __restrict__ W2h, u16* __restrict__ W2l,
    float* __restrict__ scale2)
{
    const int blk = blockIdx.x, t = threadIdx.x;
    if (blk < 1024) {                       // A planes: 2048 floats per block
        const float* src; u16 *dh, *dl; int a;
        if (blk < 512) { src = query; dh = Aqh; dl = Aql; a = blk; }
        else           { src = value; dh = Avh; dl = Avl; a = blk - 512; }
        const float4* s4 = (const float4*)src + (size_t)a * 512;
        #pragma unroll
        for (int i = 0; i < 2; i++) {
            const int idx = i * 256 + t;
            const float4 x = s4[idx];
            ushort4 h, l;
            h.x = f2bf(x.x); l.x = f2bf(x.x - bf2f(h.x));
            h.y = f2bf(x.y); l.y = f2bf(x.y - bf2f(h.y));
            h.z = f2bf(x.z); l.z = f2bf(x.z - bf2f(h.z));
            h.w = f2bf(x.w); l.w = f2bf(x.w - bf2f(h.w));
            ((ushort4*)dh)[(size_t)a * 512 + idx] = h;
            ((ushort4*)dl)[(size_t)a * 512 + idx] = l;
        }
    } else if (blk < 1280) {                // W: 32x32 transpose tiles, CSC folded
        __shared__ float tile[32][33];
        const int w = blk - 1024;
        const float* W = (w >> 7) ? W2 : W1;
        u16* oh = (w >> 7) ? W2h : W1h;
        u16* ol = (w >> 7) ? W2l : W1l;
        const int tl = w & 127;
        const int k0 = (tl >> 3) * 32, n0 = (tl & 7) * 32;
        const int kl = t >> 5, nl = t & 31;
        #pragma unroll
        for (int r = 0; r < 4; r++)
            tile[kl + 8 * r][nl] = CSC * W[(size_t)(k0 + kl + 8 * r) * UU + n0 + nl];
        __syncthreads();
        const int nr = t >> 5, kc = t & 31;
        #pragma unroll
        for (int r = 0; r < 4; r++) {
            const float v = tile[kc][nr + 8 * r];
            const u16 h = f2bf(v), lo = f2bf(v - bf2f(h));
            oh[(size_t)(n0 + nr + 8 * r) * DQ + k0 + kc] = h;
            ol[(size_t)(n0 + nr + 8 * r) * DQ + k0 + kc] = lo;
        }
    } else {                                // scale2 = -2*scale
        scale2[t] = -2.0f * scale[t];
    }
}

__global__ void fill_scale2(const float* __restrict__ scale, float* __restrict__ scale2) {
    scale2[threadIdx.x] = -2.0f * scale[threadIdx.x];
}

// ---- proj via split-bf16 MFMA: C = A@W' (W' pre-scaled by CSC), 3 terms.
// Block 256 thr = 4 waves (2x2), 64x64 tile, K-chunks of 32 via 16x16x32 MFMA.
// z=0 -> qp row-major; z=1 -> kT interleaved [b][u/4][j][4] via LDS bounce.
__global__ __launch_bounds__(256) void proj_mfma(
    const u16* __restrict__ Aqh, const u16* __restrict__ Aql,
    const u16* __restrict__ Avh, const u16* __restrict__ Avl,
    const u16* __restrict__ W1h, const u16* __restrict__ W1l,
    const u16* __restrict__ W2h, const u16* __restrict__ W2l,
    float* __restrict__ qp, float* __restrict__ kT)
{
    __shared__ __align__(16) char raw[20480];
    u16* As_h = (u16*)raw;               // [64][40] (80B rows, 16B-aligned)
    u16* As_l = (u16*)(raw + 5120);
    u16* Ws_h = (u16*)(raw + 10240);
    u16* Ws_l = (u16*)(raw + 15360);
    float* fin = (float*)raw;            // [64][68], aliases staging after final barrier

    const int z = blockIdx.z;
    const u16 *Ah, *Alo, *Wh, *Wl;
    if (z == 0) { Ah = Aqh; Alo = Aql; Wh = W1h; Wl = W1l; }
    else        { Ah = Avh; Alo = Avl; Wh = W2h; Wl = W2l; }

    const int t = threadIdx.x;
    const int m0 = blockIdx.x * 64, n0 = blockIdx.y * 64;
    const int row = t >> 2, koff = (t & 3) * 8;     // staging map: 4 thr per row
    const int wave = t >> 6, ln = t & 15, qd = (t & 63) >> 4;
    const int wm = wave >> 1, wn = wave & 1;

    f32x4 acc[2][2] = {};
    const size_t abase = (size_t)(m0 + row) * DQ + koff;
    const size_t wbase = (size_t)(n0 + row) * DQ + koff;

    for (int k0 = 0; k0 < DQ; k0 += 32) {
        const uint4 va_h = *(const uint4*)&Ah [abase + k0];
        const uint4 va_l = *(const uint4*)&Alo[abase + k0];
        const uint4 vw_h = *(const uint4*)&Wh [wbase + k0];
        const uint4 vw_l = *(const uint4*)&Wl [wbase + k0];
        __syncthreads();
        *(uint4*)&As_h[row * 40 + koff] = va_h;
        *(uint4*)&As_l[row * 40 + koff] = va_l;
        *(uint4*)&Ws_h[row * 40 + koff] = vw_h;
        *(uint4*)&Ws_l[row * 40 + koff] = vw_l;
        __syncthreads();
        bf16x8 ah[2], al[2], bh[2], bl[2];
        #pragma unroll
        for (int i = 0; i < 2; i++) {
            const int ar = (wm * 32 + i * 16 + ln) * 40 + qd * 8;
            const int br = (wn * 32 + i * 16 + ln) * 40 + qd * 8;
            ah[i] = *(const bf16x8*)&As_h[ar];
            al[i] = *(const bf16x8*)&As_l[ar];
            bh[i] = *(const bf16x8*)&Ws_h[br];
            bl[i] = *(const bf16x8*)&Ws_l[br];
        }
        #pragma unroll
        for (int i = 0; i < 2; i++) {
            #pragma unroll
            for (int j = 0; j < 2; j++) {
                acc[i][j] = __builtin_amdgcn_mfma_f32_16x16x32_bf16(ah[i], bh[j], acc[i][j], 0, 0, 0);
                acc[i][j] = __builtin_amdgcn_mfma_f32_16x16x32_bf16(ah[i], bl[j], acc[i][j], 0, 0, 0);
                acc[i][j] = __builtin_amdgcn_mfma_f32_16x16x32_bf16(al[i], bh[j], acc[i][j], 0, 0, 0);
            }
        }
    }

    if (z == 0) {
        #pragma unroll
        for (int i = 0; i < 2; i++) {
            #pragma unroll
            for (int j = 0; j < 2; j++) {
                #pragma unroll
                for (int r = 0; r < 4; r++) {
                    const int m = m0 + wm * 32 + i * 16 + qd * 4 + r;
                    const int n = n0 + wn * 32 + j * 16 + ln;
                    qp[(size_t)m * UU + n] = acc[i][j][r];
                }
            }
        }
    } else {
        __syncthreads();   // frag reads done before aliasing staging with fin
        #pragma unroll
        for (int i = 0; i < 2; i++) {
            #pragma unroll
            for (int j = 0; j < 2; j++) {
                #pragma unroll
                for (int r = 0; r < 4; r++) {
                    const int ml = wm * 32 + i * 16 + qd * 4 + r;
                    const int nl = wn * 32 + j * 16 + ln;
                    fin[ml * 68 + nl] = acc[i][j][r];
                }
            }
        }
        __syncthreads();
        const int b = m0 >> 9, j0 = m0 & 511;
        #pragma unroll
        for (int i = 0; i < 4; i++) {
            const int idx = i * 256 + t;
            const int jl = idx & 63, u4 = idx >> 6;   // u4 0..15
            const float4 v = *(const float4*)&fin[jl * 68 + u4 * 4];
            ((float4*)kT)[(size_t)(b * (UU / 4) + (n0 >> 2) + u4) * TK + j0 + jl] = v;
        }
    }
}

// ---- fallback proj (R4 structure) if workspace too small for the MFMA path
__global__ __launch_bounds__(512) void proj_fb(
    const float* __restrict__ Aq, const float* __restrict__ Av,
    const float* __restrict__ W1, const float* __restrict__ W2,
    float* __restrict__ qp, float* __restrict__ kT)
{
    __shared__ float part[8][UU];
    __shared__ float fin[8][UU + 4];
    const float* A; const float* W;
    const int z = blockIdx.z;
    if (z == 0) { A = Aq; W = W1; } else { A = Av; W = W2; }
    const int n  = threadIdx.x;
    const int kh = __builtin_amdgcn_readfirstlane(threadIdx.y);
    const int m0 = blockIdx.x * 8;
    const int kb = kh * KH;
    const float* a0 = A + (size_t)m0 * DQ + kb;
    const float* w0 = W + (size_t)kb * UU + n;
    float acc[8] = {};
    float wcur[16], wnxt[16];
    #pragma unroll
    for (int j = 0; j < 16; j++) wcur[j] = w0[(size_t)j * UU];
    for (int k0 = 0; k0 < KH; k0 += 32) {
        #pragma unroll
        for (int j = 0; j < 16; j++) wnxt[j] = w0[(size_t)(k0 + 16 + j) * UU];
        #pragma unroll
        for (int kk = 0; kk < 16; kk += 4) {
            #pragma unroll
            for (int r = 0; r < 8; r++) {
                const float4 a = *(const float4*)&a0[(size_t)r * DQ + k0 + kk];
                acc[r] = fmaf(a.x, wcur[kk], fmaf(a.y, wcur[kk + 1],
                         fmaf(a.z, wcur[kk + 2], fmaf(a.w, wcur[kk + 3], acc[r]))));
            }
        }
        const int k2 = (k0 + 32 < KH) ? (k0 + 32) : k0;
        #pragma unroll
        for (int j = 0; j < 16; j++) wcur[j] = w0[(size_t)(k2 + j) * UU];
        #pragma unroll
        for (int kk = 0; kk < 16; kk += 4) {
            #pragma unroll
            for (int r = 0; r < 8; r++) {
                const float4 a = *(const float4*)&a0[(size_t)r * DQ + k0 + 16 + kk];
                acc[r] = fmaf(a.x, wnxt[kk], fmaf(a.y, wnxt[kk + 1],
                         fmaf(a.z, wnxt[kk + 2], fmaf(a.w, wnxt[kk + 3], acc[r]))));
            }
        }
    }
    if (kh == 1) {
        #pragma unroll
        for (int r = 0; r < 8; r++) part[r][n] = acc[r];
    }
    __syncthreads();
    if (z == 0) {
        if (kh == 0) {
            #pragma unroll
            for (int r = 0; r < 8; r++)
                qp[(size_t)(m0 + r) * UU + n] = CSC * (acc[r] + part[r][n]);
        }
    } else {
        if (kh == 0) {
            #pragma unroll
            for (int r = 0; r < 8; r++) fin[r][n] = CSC * (acc[r] + part[r][n]);
        }
        __syncthreads();
        const int t = threadIdx.y * 256 + threadIdx.x;
        const int jl = t & 7, u4 = t >> 3;
        const int b = m0 >> 9, j0 = m0 & 511;
        const float4 v = *(const float4*)&fin[jl][u4 * 4];
        ((float4*)kT)[(size_t)(b * (UU / 4) + u4) * TK + j0 + jl] = v;
    }
}

// ---- attn+softmax: unpaired, fully packed (pk_add/pk_fma), scale2 = -2*scale.
// shifted_score[r][t] = sum_u scale2_u * rcp(1 + 2^(q+k))  (softmax shift-invariant).
__global__ __launch_bounds__(512) void attn_softmax(
    const float* __restrict__ qp,     // [BB, TQ, UU], pre-scaled by 2log2e
    const float* __restrict__ kT,     // [BB, UU/4, TK] of float4 (interleaved u)
    const float* __restrict__ scale2, // [UU] = -2*scale
    float* __restrict__ out)          // [BB, TQ, TK]
{
    __shared__ float redbuf[RQ][8];
    const f2 one = {1.0f, 1.0f};
    const int t  = threadIdx.x;
    const int b  = blockIdx.x >> 8;
    const int q0 = (blockIdx.x & 255) * RQ;
    const float*  qrow = qp + (size_t)(b * TQ + q0) * UU;   // wave-uniform
    const float4* kb4  = (const float4*)kT + (size_t)b * (UU / 4) * TK + t;

    f2 acc2[RQ] = {};
    float4 kbuf[2];
    kbuf[0] = kb4[0];
    kbuf[1] = kb4[TK];

    #pragma unroll 2
    for (int g = 0; g < UU / 4; g++) {
        const float4 kv = kbuf[g & 1];
        if (g + 2 < UU / 4) kbuf[g & 1] = kb4[(size_t)(g + 2) * TK];  // 2-deep prefetch
        const float4 sc4 = *(const float4*)&scale2[4 * g];            // wave-uniform
        const float* sf = (const float*)&sc4;
        const float* kf = (const float*)&kv;
        #pragma unroll
        for (int r = 0; r < RQ; r++) {
            const float4 q4 = *(const float4*)&qrow[(size_t)r * UU + 4 * g];
            const float* qf = (const float*)&q4;
            #pragma unroll
            for (int p = 0; p < 4; p += 2) {
                f2 q2, k2, s2;
                q2.x = qf[p]; q2.y = qf[p + 1];
                k2.x = kf[p]; k2.y = kf[p + 1];
                s2.x = sf[p]; s2.y = sf[p + 1];
                const f2 x = q2 + k2;          // v_pk_add_f32
                f2 e;
                e.x = fexp2(x.x); e.y = fexp2(x.y);
                const f2 d = e + one;          // v_pk_add_f32
                f2 rr;
                rr.x = frcp(d.x); rr.y = frcp(d.y);
                acc2[r] = __builtin_elementwise_fma(s2, rr, acc2[r]);  // v_pk_fma_f32
            }
        }
    }

    const int wave = t >> 6, lane = t & 63;
    float acc[RQ], m[RQ], p[RQ];
    #pragma unroll
    for (int r = 0; r < RQ; r++) acc[r] = acc2[r].x + acc2[r].y;

    // row max over 512 threads
    #pragma unroll
    for (int r = 0; r < RQ; r++) {
        float v = acc[r];
        #pragma unroll
        for (int o = 32; o > 0; o >>= 1) v = fmaxf(v, __shfl_xor(v, o));
        if (lane == 0) redbuf[r][wave] = v;
    }
    __syncthreads();
    #pragma unroll
    for (int r = 0; r < RQ; r++) {
        float v = redbuf[r][0];
        #pragma unroll
        for (int w = 1; w < 8; w++) v = fmaxf(v, redbuf[r][w]);
        m[r] = v;
    }
    __syncthreads();
    #pragma unroll
    for (int r = 0; r < RQ; r++) {
        p[r] = fexp2(L2E * (acc[r] - m[r]));
        float v = p[r];
        #pragma unroll
        for (int o = 32; o > 0; o >>= 1) v += __shfl_xor(v, o);
        if (lane == 0) redbuf[r][wave] = v;
    }
    __syncthreads();
    #pragma unroll
    for (int r = 0; r < RQ; r++) {
        float v = 0.0f;
        #pragma unroll
        for (int w = 0; w < 8; w++) v += redbuf[r][w];
        const float rinv = frcp(v);
        out[(size_t)(b * TQ + q0 + r) * TK + t] = p[r] * rinv;
    }
}

extern "C" void kernel_launch(void* const* d_in, const int* in_sizes, int n_in,
                              void* d_out, int out_size, void* d_ws, size_t ws_size,
                              hipStream_t stream) {
    const float* query = (const float*)d_in[0];
    const float* value = (const float*)d_in[1];
    const float* W1    = (const float*)d_in[2];
    const float* W2    = (const float*)d_in[3];
    const float* scale = (const float*)d_in[4];
    float* out = (float*)d_out;

    float* qp = (float*)d_ws;                        // 2 MB
    float* kT = qp + (size_t)BB * TQ * UU;           // 2 MB
    float* scale2 = (float*)((char*)d_ws + 4 * 1048576);   // 1 KB (4 KB slot)

    if (ws_size >= (size_t)WS_NEED) {
        char* base = (char*)d_ws + 4 * 1048576 + 4096;
        u16* Aqh = (u16*)(base);
        u16* Aql = (u16*)(base + 2 * 1048576);
        u16* Avh = (u16*)(base + 4 * 1048576);
        u16* Avl = (u16*)(base + 6 * 1048576);
        u16* W1h = (u16*)(base + 8 * 1048576);
        u16* W1l = (u16*)(base + 8 * 1048576 + 262144);
        u16* W2h = (u16*)(base + 8 * 1048576 + 524288);
        u16* W2l = (u16*)(base + 8 * 1048576 + 786432);
        convert<<<1281, 256, 0, stream>>>(query, value, W1, W2, scale,
                                          Aqh, Aql, Avh, Avl, W1h, W1l, W2h, W2l,
                                          scale2);
        proj_mfma<<<dim3(32, 4, 2), 256, 0, stream>>>(Aqh, Aql, Avh, Avl,
                                                      W1h, W1l, W2h, W2l, qp, kT);
    } else {
        fill_scale2<<<1, 256, 0, stream>>>(scale, scale2);
        proj_fb<<<dim3((BB * TQ) / 8, 1, 2), dim3(256, 2), 0, stream>>>(
            query, value, W1, W2, qp, kT);
    }
    attn_softmax<<<dim3(BB * TQ / RQ), 512, 0, stream>>>(qp, kT, scale2, out);
}

// Round 9
// 121.274 us; speedup vs baseline: 1.1112x; 1.1112x over previous
//
#include <hip/hip_runtime.h>

#define BB 4
#define TQ 512
#define TK 512
#define DQ 512
#define UU 256
#define CSC 2.8853900817779268f   // 2*log2(e): Eq=2^(CSC*q), Ek=2^(CSC*k), e^{2y}=Eq*Ek
#define L2E 1.4426950408889634f
#define RQ 2

typedef unsigned short u16;
typedef unsigned int u32;
typedef short bf16x8 __attribute__((ext_vector_type(8)));
typedef float f32x4 __attribute__((ext_vector_type(4)));

__device__ __forceinline__ float fexp2(float x) { return __builtin_amdgcn_exp2f(x); }
__device__ __forceinline__ float frcp(float x)  { return __builtin_amdgcn_rcpf(x); }
// pack the high 16 bits of two fp32 words: low16 = a.hi16, high16 = b.hi16
__device__ __forceinline__ u32 pkhi(u32 a, u32 b) {
    return (b & 0xffff0000u) | (a >> 16);
}

// Fused convert+projection via split-bf16 MFMA (truncation split, 3 terms):
// z=0: Eq[b*TQ+i][u] = 2^(CSC * (query@W1))   row-major
// z=1: Ek interleaved [b][u/4][j][4] (float4 per (u-group, col))
// Block 256 thr = 4 waves (2x2), 64x64 tile. A: fp32 global -> inline split -> LDS.
// W: per-lane direct global fragment loads (lanes 0-15 = consecutive cols, coalesced).
__global__ __launch_bounds__(256) void proj_fused(
    const float* __restrict__ Aq, const float* __restrict__ Av,
    const float* __restrict__ W1, const float* __restrict__ W2,
    float* __restrict__ Eq, float* __restrict__ Ek)
{
    __shared__ __align__(16) char raw[17408];
    u16* As_h = (u16*)raw;               // [64][40] u16 (80B rows, 16B-aligned frags)
    u16* As_l = (u16*)(raw + 5120);
    float* fin = (float*)raw;            // [64][68] f32, aliases staging after barrier

    const int z = blockIdx.z;
    const float* A = z ? Av : Aq;
    const float* W = z ? W2 : W1;

    const int t = threadIdx.x;
    const int m0 = blockIdx.x * 64, n0 = blockIdx.y * 64;
    const int row = t >> 2, kseg = (t & 3) * 8;     // A staging: 4 thr/row, 8 k each
    const int wave = t >> 6, ln = t & 15, qd = (t & 63) >> 4;
    const int wm = wave >> 1, wn = wave & 1;

    const size_t abase = (size_t)(m0 + row) * DQ + kseg;
    const int ncol = n0 + wn * 32 + ln;             // B-frag col (j adds 16)

    f32x4 acc[2][2] = {};

    for (int k0 = 0; k0 < DQ; k0 += 32) {
        const float4 av0 = *(const float4*)&A[abase + k0];
        const float4 av1 = *(const float4*)&A[abase + k0 + 4];
        float wv[2][8];
        #pragma unroll
        for (int j = 0; j < 2; j++) {
            #pragma unroll
            for (int e = 0; e < 8; e++)
                wv[j][e] = W[(size_t)(k0 + qd * 8 + e) * UU + ncol + j * 16];
        }
        __syncthreads();   // previous iteration's LDS reads done
        {
            const float f[8] = {av0.x, av0.y, av0.z, av0.w, av1.x, av1.y, av1.z, av1.w};
            u32 x[8], lx[8];
            #pragma unroll
            for (int e = 0; e < 8; e++) {
                x[e]  = __float_as_uint(f[e]);
                lx[e] = __float_as_uint(f[e] - __uint_as_float(x[e] & 0xffff0000u));
            }
            uint4 hw, lw;
            hw.x = pkhi(x[0], x[1]);  hw.y = pkhi(x[2], x[3]);
            hw.z = pkhi(x[4], x[5]);  hw.w = pkhi(x[6], x[7]);
            lw.x = pkhi(lx[0], lx[1]); lw.y = pkhi(lx[2], lx[3]);
            lw.z = pkhi(lx[4], lx[5]); lw.w = pkhi(lx[6], lx[7]);
            *(uint4*)&As_h[row * 40 + kseg] = hw;
            *(uint4*)&As_l[row * 40 + kseg] = lw;
        }
        __syncthreads();

        bf16x8 ah[2], al[2], bh[2], bl[2];
        #pragma unroll
        for (int i = 0; i < 2; i++) {
            const int ar = (wm * 32 + i * 16 + ln) * 40 + qd * 8;
            ah[i] = *(const bf16x8*)&As_h[ar];
            al[i] = *(const bf16x8*)&As_l[ar];
        }
        #pragma unroll
        for (int j = 0; j < 2; j++) {
            u32 y[8], ly[8];
            #pragma unroll
            for (int e = 0; e < 8; e++) {
                y[e]  = __float_as_uint(wv[j][e]);
                ly[e] = __float_as_uint(wv[j][e] - __uint_as_float(y[e] & 0xffff0000u));
            }
            union { uint4 u; bf16x8 v; } h, l;
            h.u.x = pkhi(y[0], y[1]);  h.u.y = pkhi(y[2], y[3]);
            h.u.z = pkhi(y[4], y[5]);  h.u.w = pkhi(y[6], y[7]);
            l.u.x = pkhi(ly[0], ly[1]); l.u.y = pkhi(ly[2], ly[3]);
            l.u.z = pkhi(ly[4], ly[5]); l.u.w = pkhi(ly[6], ly[7]);
            bh[j] = h.v; bl[j] = l.v;
        }
        #pragma unroll
        for (int i = 0; i < 2; i++) {
            #pragma unroll
            for (int j = 0; j < 2; j++) {
                acc[i][j] = __builtin_amdgcn_mfma_f32_16x16x32_bf16(ah[i], bh[j], acc[i][j], 0, 0, 0);
                acc[i][j] = __builtin_amdgcn_mfma_f32_16x16x32_bf16(ah[i], bl[j], acc[i][j], 0, 0, 0);
                acc[i][j] = __builtin_amdgcn_mfma_f32_16x16x32_bf16(al[i], bh[j], acc[i][j], 0, 0, 0);
            }
        }
    }

    if (z == 0) {
        #pragma unroll
        for (int i = 0; i < 2; i++) {
            #pragma unroll
            for (int j = 0; j < 2; j++) {
                #pragma unroll
                for (int r = 0; r < 4; r++) {
                    const int m = m0 + wm * 32 + i * 16 + qd * 4 + r;
                    const int n = n0 + wn * 32 + j * 16 + ln;
                    Eq[(size_t)m * UU + n] = fexp2(CSC * acc[i][j][r]);
                }
            }
        }
    } else {
        __syncthreads();   // frag reads done before aliasing staging with fin
        #pragma unroll
        for (int i = 0; i < 2; i++) {
            #pragma unroll
            for (int j = 0; j < 2; j++) {
                #pragma unroll
                for (int r = 0; r < 4; r++) {
                    const int ml = wm * 32 + i * 16 + qd * 4 + r;
                    const int nl = wn * 32 + j * 16 + ln;
                    fin[ml * 68 + nl] = fexp2(CSC * acc[i][j][r]);
                }
            }
        }
        __syncthreads();
        const int b = m0 >> 9, j0 = m0 & 511;
        #pragma unroll
        for (int i = 0; i < 4; i++) {
            const int idx = i * 256 + t;
            const int jl = idx & 63, u4 = idx >> 6;   // u4 0..15
            const float4 v = *(const float4*)&fin[jl * 68 + u4 * 4];
            ((float4*)Ek)[(size_t)(b * (UU / 4) + (n0 >> 2) + u4) * TK + j0 + jl] = v;
        }
    }
}

// attn+softmax: e^{2y} = Eq*Ek (no per-element exp!).
// shifted_score[r][t] = -2 * sum_u scale_u * rcp(1 + Eq*Ek)   (softmax shift-invariant:
// true score differs by the constant sum_u scale_u). Per element: mul, add, rcp, fmac.
__global__ __launch_bounds__(512) void attn_softmax(
    const float* __restrict__ Eq,    // [BB, TQ, UU]
    const float* __restrict__ Ek,    // [BB, UU/4, TK] of float4 (interleaved u)
    const float* __restrict__ scale, // [UU]
    float* __restrict__ out)         // [BB, TQ, TK]
{
    __shared__ float redbuf[RQ][8];
    const int t  = threadIdx.x;
    const int b  = blockIdx.x >> 8;            // 256 blocks per b
    const int q0 = (blockIdx.x & 255) * RQ;
    const float*  qrow = Eq + (size_t)(b * TQ + q0) * UU;   // wave-uniform
    const float4* kb4  = (const float4*)Ek + (size_t)b * (UU / 4) * TK + t;

    float acc[RQ] = {};
    float4 kbuf[2];
    kbuf[0] = kb4[0];
    kbuf[1] = kb4[TK];

    #pragma unroll 2
    for (int g = 0; g < UU / 4; g++) {
        const float4 kv = kbuf[g & 1];
        if (g + 2 < UU / 4) kbuf[g & 1] = kb4[(size_t)(g + 2) * TK];  // 2-deep prefetch
        const float4 sc4 = *(const float4*)&scale[4 * g];             // wave-uniform
        const float* sf = (const float*)&sc4;
        const float* kf = (const float*)&kv;
        #pragma unroll
        for (int r = 0; r < RQ; r++) {
            const float4 q4 = *(const float4*)&qrow[(size_t)r * UU + 4 * g];
            const float* qf = (const float*)&q4;
            #pragma unroll
            for (int p = 0; p < 4; p++) {
                const float e = qf[p] * kf[p];          // e^{2y}
                const float d = e + 1.0f;
                acc[r] = fmaf(sf[p], frcp(d), acc[r]);  // += scale/(1+e)
            }
        }
    }
    #pragma unroll
    for (int r = 0; r < RQ; r++) acc[r] *= -2.0f;

    const int wave = t >> 6, lane = t & 63;
    float m[RQ], p[RQ];

    // row max over 512 threads
    #pragma unroll
    for (int r = 0; r < RQ; r++) {
        float v = acc[r];
        #pragma unroll
        for (int o = 32; o > 0; o >>= 1) v = fmaxf(v, __shfl_xor(v, o));
        if (lane == 0) redbuf[r][wave] = v;
    }
    __syncthreads();
    #pragma unroll
    for (int r = 0; r < RQ; r++) {
        float v = redbuf[r][0];
        #pragma unroll
        for (int w = 1; w < 8; w++) v = fmaxf(v, redbuf[r][w]);
        m[r] = v;
    }
    __syncthreads();

    // exp and row sum
    #pragma unroll
    for (int r = 0; r < RQ; r++) {
        p[r] = fexp2(L2E * (acc[r] - m[r]));
        float v = p[r];
        #pragma unroll
        for (int o = 32; o > 0; o >>= 1) v += __shfl_xor(v, o);
        if (lane == 0) redbuf[r][wave] = v;
    }
    __syncthreads();
    #pragma unroll
    for (int r = 0; r < RQ; r++) {
        float v = 0.0f;
        #pragma unroll
        for (int w = 0; w < 8; w++) v += redbuf[r][w];
        const float rinv = frcp(v);
        out[(size_t)(b * TQ + q0 + r) * TK + t] = p[r] * rinv;
    }
}

extern "C" void kernel_launch(void* const* d_in, const int* in_sizes, int n_in,
                              void* d_out, int out_size, void* d_ws, size_t ws_size,
                              hipStream_t stream) {
    const float* query = (const float*)d_in[0];
    const float* value = (const float*)d_in[1];
    const float* W1    = (const float*)d_in[2];
    const float* W2    = (const float*)d_in[3];
    const float* scale = (const float*)d_in[4];
    float* out = (float*)d_out;

    float* Eq = (float*)d_ws;                     // [BB*TQ, UU]      2 MB
    float* Ek = Eq + (size_t)BB * TQ * UU;        // [BB,UU/4,TK] f4  2 MB
    (void)ws_size;  // needs 4 MB; harness provides >=13 MB (verified R7/R8)

    proj_fused<<<dim3(32, 4, 2), 256, 0, stream>>>(query, value, W1, W2, Eq, Ek);
    attn_softmax<<<dim3(BB * TQ / RQ), 512, 0, stream>>>(Eq, Ek, scale, out);
}